// Round 16
// baseline (8712.743 us; speedup 1.0000x reference)
//
#include <hip/hip_runtime.h>

#define V_ 32000
#define E_ 256
#define U_ 512
#define B_ 64
#define T_ 256
#define G_ 2048      // 4*U

#define RSTR 516     // R rows / scan-h rows: 512 data + 4 pad floats
#define ASTR 260     // precompute A rows: 256 data + 4 pad
#define WESTR 132    // We rows: 128 data + 4 pad
#define PSTR 36      // Psum row stride (32 gc + 4 pad) -> 2-way banks max

// d_ws layout:
//   [0, 512KB)   : hbuf float [2][2][B_][U_] (cur, dir, b, u)
//   [512KB, +16K): barrier slots, u32 at (grp*64+mem)*16 (64B stride)
//   [1MB, ...)   : xz chunk buffer [256 blk][CH][32 gc][32 b] floats
// Coherence (NO L2 invalidation anywhere):
//   h stores  : relaxed agent-scope atomic stores (write-through to MALL)
//   h loads   : relaxed agent-scope atomic loads (L2-bypassing, MALL-coherent)
//   slots     : relaxed agent-scope atomics, single-writer 64B-strided
// v16 = v14 with register allocation PINNED at 4 waves/EU (VGPR<=128):
//   r14's regression was VGPR_Count=64 + scratch spills (FETCH doubled), a
//   __launch_bounds__(1024,1) allocator artifact — not a TLP refutation.
//   16 waves, k-split 16, per-wave poll of 4 producers, ds_add_f32 k-reduce.

#define GLDS16(gsrc, ldst) __builtin_amdgcn_global_load_lds( \
    (const __attribute__((address_space(1))) void*)(gsrc),    \
    (__attribute__((address_space(3))) void*)(ldst), 16, 0, 0)

__global__
__attribute__((amdgpu_flat_work_group_size(1024, 1024)))
__attribute__((amdgpu_waves_per_eu(4, 4)))
void bilstm_kernel(const int* __restrict__ x,
                   const float* __restrict__ emb,
                   const float* __restrict__ Wf, const float* __restrict__ Rf,
                   const float* __restrict__ bf,
                   const float* __restrict__ Wb, const float* __restrict__ Rb,
                   const float* __restrict__ bb,
                   float* __restrict__ out, float* __restrict__ hbuf,
                   unsigned* __restrict__ bar, float* __restrict__ xz,
                   int CH)
{
    __shared__ __align__(16) float Rl[32 * RSTR];     // 66,048 B
    __shared__ __align__(16) float HA[64 * ASTR];     // 66,560 B (A / scan-h / pre-reduce)
    __shared__ __align__(16) float Wel[32 * WESTR];   // 16,896 B (W-half / scan Psum)

    const int blk = blockIdx.x;
    const int dir = blk >> 7;
    const int rem = blk & 127;
    const int u0 = (rem >> 1) * 8;
    const int b0base = (rem & 1) * 32;
    const int grp = dir * 2 + (rem & 1);
    const int mem = rem >> 1;
    unsigned* myslot = bar + (grp * 64 + mem) * 16;

    const int tid   = threadIdx.x;       // 1024
    const int wv    = tid >> 6;          // wave 0..15 (owns 32-float k-slice)
    const int lane  = tid & 63;
    const int uu    = lane & 7;          // gate-col sub-index
    const int blgrp = lane >> 3;         // 0..7
    const int blf   = tid >> 3;          // finalize mapping (valid tid<256): batch 0..31
    const int fuu   = tid & 7;           // finalize mapping: u sub-index

    const float* Wd = dir ? Wb : Wf;
    const float* Rd = dir ? Rb : Rf;
    const float* bd = dir ? bb : bf;

    // ---- one-time: stage R transposed into LDS (all 32 thread-groups) ----
    {
        const int sgc  = tid & 31;
        const int gcol = ((sgc >> 3) * 512) + u0 + (sgc & 7);
        for (int k = tid >> 5; k < 512; k += 32)
            Rl[sgc * RSTR + k] = Rd[(size_t)k * G_ + gcol];
    }
    float bias4[4];
    #pragma unroll
    for (int g = 0; g < 4; ++g) bias4[g] = bd[g * 512 + u0 + fuu];

    float c_reg = 0.0f;
    float h_prev = 0.0f;                 // this thread's own h cell (blf, u0+fuu)
    const float4* Rl4  = reinterpret_cast<const float4*>(Rl);
    const float4* HA4  = reinterpret_cast<const float4*>(HA);
    const float4* Wel4 = reinterpret_cast<const float4*>(Wel);
    float4* HAw4 = reinterpret_cast<float4*>(HA);   // staging writes
    float*  Psum = Wel;                             // scan scalar reduce [32][PSTR]
    float4* P4p = reinterpret_cast<float4*>(HA);    // precompute reduce (64 KB)

    __syncthreads();

    const int nch = T_ / CH;
    for (int ch = 0; ch < nch; ++ch) {
        // ===== precompute xz = e@W for this chunk (waves 0-7 only) =====
        const int nat = CH >> 1;                     // A-tiles of 2t x 32b
        for (int at = 0; at < nat; ++at) {
            __syncthreads();                         // HA & Wel free
            if (tid < 512) {
                for (int i = 0; i < 8; ++i) {
                    int rr   = wv * 8 + i;
                    int tloc = at * 2 + (rr >> 5);
                    int bla  = rr & 31;
                    int sg   = ch * CH + tloc;
                    int tea  = dir ? (T_ - 1 - sg) : sg;
                    int tok  = x[(b0base + bla) * T_ + tea];
                    GLDS16(emb + (size_t)tok * E_ + lane * 4, HA + rr * ASTR);
                }
            }
            float pacc[8][4];
            #pragma unroll
            for (int j = 0; j < 8; ++j)
                #pragma unroll
                for (int g = 0; g < 4; ++g) pacc[j][g] = 0.0f;

            for (int kh = 0; kh < 2; ++kh) {
                if (kh) __syncthreads();             // Wel half-0 reads done
                if (tid < 512) {
                    const int sgc  = tid & 31;
                    const int gcol = ((sgc >> 3) * 512) + u0 + (sgc & 7);
                    for (int kk = tid >> 5; kk < 128; kk += 16)
                        Wel[sgc * WESTR + kk] = Wd[(size_t)(kh * 128 + kk) * G_ + gcol];
                }
                __syncthreads();                     // A (vmcnt drained) + Wel ready
                if (tid < 512) {
                    #pragma unroll
                    for (int k4 = 0; k4 < 4; ++k4) {
                        const int kw = wv * 4 + k4;
                        float4 w0 = Wel4[(0 * 8 + uu) * 33 + kw];
                        float4 w1 = Wel4[(1 * 8 + uu) * 33 + kw];
                        float4 w2 = Wel4[(2 * 8 + uu) * 33 + kw];
                        float4 w3 = Wel4[(3 * 8 + uu) * 33 + kw];
                        #pragma unroll
                        for (int j = 0; j < 8; ++j) {
                            float4 a = HA4[(blgrp + 8 * j) * 65 + kh * 32 + kw];
                            pacc[j][0] = fmaf(w0.x,a.x,pacc[j][0]); pacc[j][0] = fmaf(w0.y,a.y,pacc[j][0]);
                            pacc[j][0] = fmaf(w0.z,a.z,pacc[j][0]); pacc[j][0] = fmaf(w0.w,a.w,pacc[j][0]);
                            pacc[j][1] = fmaf(w1.x,a.x,pacc[j][1]); pacc[j][1] = fmaf(w1.y,a.y,pacc[j][1]);
                            pacc[j][1] = fmaf(w1.z,a.z,pacc[j][1]); pacc[j][1] = fmaf(w1.w,a.w,pacc[j][1]);
                            pacc[j][2] = fmaf(w2.x,a.x,pacc[j][2]); pacc[j][2] = fmaf(w2.y,a.y,pacc[j][2]);
                            pacc[j][2] = fmaf(w2.z,a.z,pacc[j][2]); pacc[j][2] = fmaf(w2.w,a.w,pacc[j][2]);
                            pacc[j][3] = fmaf(w3.x,a.x,pacc[j][3]); pacc[j][3] = fmaf(w3.y,a.y,pacc[j][3]);
                            pacc[j][3] = fmaf(w3.z,a.z,pacc[j][3]); pacc[j][3] = fmaf(w3.w,a.w,pacc[j][3]);
                        }
                    }
                }
            }
            __syncthreads();                         // A reads done -> HA reusable
            if (tid < 512) {
                #pragma unroll
                for (int j = 0; j < 8; ++j)
                    P4p[(wv * 64 + blgrp + 8 * j) * 8 + uu] =
                        float4{pacc[j][0], pacc[j][1], pacc[j][2], pacc[j][3]};
            }
            __syncthreads();                         // partials ready
            if (tid < 512) {
                const int r   = tid >> 3;            // token row 0..63
                const int uq  = tid & 7;
                const int tl  = at * 2 + (r >> 5);
                const int bla = r & 31;
                float* dst = xz + ((size_t)blk * CH + tl) * 1024;
                float4 s = P4p[(0 * 64 + r) * 8 + uq];
                #pragma unroll
                for (int q = 1; q < 8; ++q) {
                    float4 p = P4p[(q * 64 + r) * 8 + uq];
                    s.x += p.x; s.y += p.y; s.z += p.z; s.w += p.w;
                }
                dst[(0 * 8 + uq) * 32 + bla] = s.x;
                dst[(1 * 8 + uq) * 32 + bla] = s.y;
                dst[(2 * 8 + uq) * 32 + bla] = s.z;
                dst[(3 * 8 + uq) * 32 + bla] = s.w;
            }
        }
        // zero Psum (32*36 = 1152 floats incl pads) for the scan's ds_add
        if (tid < 576) { Psum[tid] = 0.0f; Psum[tid + 576] = 0.0f; }
        __syncthreads();

        // ============ scan CH steps (16 waves, ds_add reduce) ============
        for (int sc = 0; sc < CH; ++sc) {
            const int s   = ch * CH + sc;
            const int te  = dir ? (T_ - 1 - s) : s;
            const int cur = s & 1, nxt = cur ^ 1;

            // hoisted, barrier-independent (finalize threads only)
            int mtok = 0;
            float xzv[4] = {0.f, 0.f, 0.f, 0.f};
            if (tid < 256) {
                mtok = x[(b0base + blf) * T_ + te];
                const float* xzp = xz + ((size_t)blk * CH + sc) * 1024;
                #pragma unroll
                for (int g = 0; g < 4; ++g)
                    xzv[g] = xzp[(g * 8 + fuu) * 32 + blf] + bias4[g];
            }

            // per-wave poll: ONLY this wave's 4 producers (u-cols [wv*32,wv*32+32))
            if (s > 0) {
                unsigned* slot = bar + (grp * 64 + wv * 4 + (lane & 3)) * 16;
                while (__hip_atomic_load(slot, __ATOMIC_RELAXED,
                                         __HIP_MEMORY_SCOPE_AGENT) < (unsigned)s)
                    __builtin_amdgcn_s_sleep(1);
            }

            // per-wave stage of own k-slice: 32 rows x 8 float4-cols, no barrier.
            {
                const float* hsrc = hbuf + ((size_t)(cur * 2 + dir) * B_ + b0base) * U_;
                const int cl = lane & 7;
                const int rl = lane >> 3;
                #pragma unroll
                for (int i = 0; i < 4; ++i) {
                    const int row = rl + 8 * i;
                    const unsigned long long* p = (const unsigned long long*)
                        (hsrc + (size_t)row * U_ + (wv * 8 + cl) * 4);
                    unsigned long long a = __hip_atomic_load(p,     __ATOMIC_RELAXED,
                                                             __HIP_MEMORY_SCOPE_AGENT);
                    unsigned long long b = __hip_atomic_load(p + 1, __ATOMIC_RELAXED,
                                                             __HIP_MEMORY_SCOPE_AGENT);
                    float2 fa = __builtin_bit_cast(float2, a);
                    float2 fb = __builtin_bit_cast(float2, b);
                    HAw4[row * 129 + wv * 8 + cl] = float4{fa.x, fa.y, fb.x, fb.y};
                }
            }
            // GEMM reads only this wave's staged cols -> wave-local lgkmcnt ordering.

            // partial z: this wave's 32-float k-slice, rows blgrp+8j, cols g*8+uu
            float pz[4][4];
            #pragma unroll
            for (int j = 0; j < 4; ++j)
                #pragma unroll
                for (int g = 0; g < 4; ++g) pz[j][g] = 0.0f;
            const int kbase = wv * 8;
            #pragma unroll
            for (int k4 = 0; k4 < 8; ++k4) {
                const int kk = kbase + k4;
                float4 h0 = HA4[(blgrp + 8 * 0) * 129 + kk];
                float4 h1 = HA4[(blgrp + 8 * 1) * 129 + kk];
                float4 h2 = HA4[(blgrp + 8 * 2) * 129 + kk];
                float4 h3 = HA4[(blgrp + 8 * 3) * 129 + kk];
                #pragma unroll
                for (int g = 0; g < 4; ++g) {
                    float4 w = Rl4[(g * 8 + uu) * 129 + kk];
                    pz[0][g] = fmaf(w.x,h0.x,pz[0][g]); pz[0][g] = fmaf(w.y,h0.y,pz[0][g]);
                    pz[0][g] = fmaf(w.z,h0.z,pz[0][g]); pz[0][g] = fmaf(w.w,h0.w,pz[0][g]);
                    pz[1][g] = fmaf(w.x,h1.x,pz[1][g]); pz[1][g] = fmaf(w.y,h1.y,pz[1][g]);
                    pz[1][g] = fmaf(w.z,h1.z,pz[1][g]); pz[1][g] = fmaf(w.w,h1.w,pz[1][g]);
                    pz[2][g] = fmaf(w.x,h2.x,pz[2][g]); pz[2][g] = fmaf(w.y,h2.y,pz[2][g]);
                    pz[2][g] = fmaf(w.z,h2.z,pz[2][g]); pz[2][g] = fmaf(w.w,h2.w,pz[2][g]);
                    pz[3][g] = fmaf(w.x,h3.x,pz[3][g]); pz[3][g] = fmaf(w.y,h3.y,pz[3][g]);
                    pz[3][g] = fmaf(w.z,h3.z,pz[3][g]); pz[3][g] = fmaf(w.w,h3.w,pz[3][g]);
                }
            }

            // k-reduce: ds_add_f32 into Psum[32][PSTR] (2-way banks, free)
            #pragma unroll
            for (int j = 0; j < 4; ++j)
                #pragma unroll
                for (int g = 0; g < 4; ++g)
                    atomicAdd(&Psum[(blgrp + 8 * j) * PSTR + g * 8 + uu], pz[j][g]);

            __syncthreads();                         // BAR_r: all adds complete

            if (tid < 256) {
                const int pbase = blf * PSTR + fuu;
                float zi = Psum[pbase + 0];  Psum[pbase + 0]  = 0.0f;
                float zf = Psum[pbase + 8];  Psum[pbase + 8]  = 0.0f;
                float zg = Psum[pbase + 16]; Psum[pbase + 16] = 0.0f;
                float zo = Psum[pbase + 24]; Psum[pbase + 24] = 0.0f;
                float fi = tanhf(zi + xzv[0]);
                float ff = tanhf(zf + xzv[1]);
                float fg = tanhf(zg + xzv[2]);
                float fo = tanhf(zo + xzv[3]);
                float cn = fmaf(ff, c_reg, fi * fg);
                float hn = fo * tanhf(cn);
                bool  m  = (mtok != 0);
                float hsel = m ? hn : h_prev;
                c_reg = m ? cn : c_reg;
                h_prev = hsel;

                const int b = b0base + blf;
                __hip_atomic_store(&hbuf[((size_t)(nxt * 2 + dir) * B_ + b) * U_ + u0 + fuu],
                                   hsel, __ATOMIC_RELAXED, __HIP_MEMORY_SCOPE_AGENT);
                out[((size_t)b * T_ + te) * 1024 + dir * 512 + u0 + fuu] = hsel;
                if (dir == 1 && s == T_ - 1)
                    out[(size_t)B_ * T_ * 1024 + (size_t)b * U_ + u0 + fuu] = hsel;
            }

            __syncthreads();       // BAR_e: vmcnt(0) drain; fences HA/Psum reuse
            if (tid == 0)
                __hip_atomic_store(myslot, (unsigned)(s + 1), __ATOMIC_RELAXED,
                                   __HIP_MEMORY_SCOPE_AGENT);
        }
    }
}

extern "C" void kernel_launch(void* const* d_in, const int* in_sizes, int n_in,
                              void* d_out, int out_size, void* d_ws, size_t ws_size,
                              hipStream_t stream) {
    const int*   x   = (const int*)d_in[0];
    const float* emb = (const float*)d_in[1];
    const float* Wf  = (const float*)d_in[2];
    const float* Rf  = (const float*)d_in[3];
    const float* bfp = (const float*)d_in[4];
    const float* Wb  = (const float*)d_in[5];
    const float* Rb  = (const float*)d_in[6];
    const float* bbp = (const float*)d_in[7];
    float* out  = (float*)d_out;
    float* hbuf = (float*)d_ws;                                   // 512 KB
    unsigned* bar = (unsigned*)((char*)d_ws + 512 * 1024);        // 16 KB
    float* xzbuf  = (float*)((char*)d_ws + (1 << 20));            // CH MB

    int CH = 32;
    while (CH > 2 && (size_t)(CH + 1) * (1 << 20) > ws_size) CH >>= 1;

    hipMemsetAsync(hbuf, 0, (size_t)2 * B_ * U_ * sizeof(float), stream);
    hipMemsetAsync(bar, 0, 4 * 64 * 16 * sizeof(unsigned), stream);

    void* args[] = {
        (void*)&x, (void*)&emb,
        (void*)&Wf, (void*)&Rf, (void*)&bfp,
        (void*)&Wb, (void*)&Rb, (void*)&bbp,
        (void*)&out, (void*)&hbuf, (void*)&bar, (void*)&xzbuf, (void*)&CH
    };
    hipLaunchCooperativeKernel((const void*)bilstm_kernel,
                               dim3(256), dim3(1024), args, 0, stream);
}

// Round 17
// 3368.773 us; speedup vs baseline: 2.5863x; 2.5863x over previous
//
#include <hip/hip_runtime.h>

#define V_ 32000
#define E_ 256
#define U_ 512
#define B_ 64
#define T_ 256
#define G_ 2048      // 4*U

#define RSTR 516     // R rows / scan-h rows: 512 data + 4 pad floats
#define ASTR 260     // precompute A rows: 256 data + 4 pad
#define WESTR 132    // We rows: 128 data + 4 pad

// d_ws layout:
//   [0, 512KB)   : hbuf float [2][2][B_][U_] (cur, dir, b, u)
//   [512KB, +16K): barrier slots, u32 at (grp*64+mem)*16 (64B stride)
//   [1MB, ...)   : xz chunk buffer [256 blk][CH][32 gc][32 b] floats
// Coherence (NO L2 invalidation anywhere):
//   h stores  : relaxed agent-scope atomic stores (write-through to MALL)
//   h loads   : relaxed agent-scope atomic loads (L2-bypassing, MALL-coherent)
//   slots     : relaxed agent-scope atomics, single-writer 64B-strided
// v17 = r9 (proven 3.38 ms) + ONE change: out[] stores moved AFTER the
// publish (they drained before the pre-publish vmcnt(0) barrier previously,
// putting ~32 scattered-cacheline store-acks on the critical path each step).
// Now: h store -> barrier (drain h) -> publish -> out stores (drain next step).

#define GLDS16(gsrc, ldst) __builtin_amdgcn_global_load_lds( \
    (const __attribute__((address_space(1))) void*)(gsrc),    \
    (__attribute__((address_space(3))) void*)(ldst), 16, 0, 0)

__global__ __launch_bounds__(512, 1)
void bilstm_kernel(const int* __restrict__ x,
                   const float* __restrict__ emb,
                   const float* __restrict__ Wf, const float* __restrict__ Rf,
                   const float* __restrict__ bf,
                   const float* __restrict__ Wb, const float* __restrict__ Rb,
                   const float* __restrict__ bb,
                   float* __restrict__ out, float* __restrict__ hbuf,
                   unsigned* __restrict__ bar, float* __restrict__ xz,
                   int CH)
{
    __shared__ __align__(16) float Rl[32 * RSTR];     // 66,048 B
    __shared__ __align__(16) float HA[64 * ASTR];     // 66,560 B (A / scan-h / pre-reduce)
    __shared__ __align__(16) float Wel[32 * WESTR];   // 16,896 B (W-half / scan-reduce)

    const int blk = blockIdx.x;
    const int dir = blk >> 7;
    const int rem = blk & 127;
    const int u0 = (rem >> 1) * 8;
    const int b0base = (rem & 1) * 32;
    const int grp = dir * 2 + (rem & 1);
    const int mem = rem >> 1;
    unsigned* myslot = bar + (grp * 64 + mem) * 16;

    const int tid   = threadIdx.x;       // 512
    const int wv    = tid >> 6;          // wave 0..7 (owns k-slice)
    const int lane  = tid & 63;
    const int uu    = lane & 7;          // gate-col sub-index
    const int blgrp = lane >> 3;         // 0..7
    const int blf   = tid >> 3;          // finalize mapping (valid tid<256): batch 0..31
    const int fuu   = tid & 7;           // finalize mapping: u sub-index

    const float* Wd = dir ? Wb : Wf;
    const float* Rd = dir ? Rb : Rf;
    const float* bd = dir ? bb : bf;

    // ---- one-time: stage R transposed into LDS ----
    {
        const int sgc  = tid & 31;
        const int gcol = ((sgc >> 3) * 512) + u0 + (sgc & 7);
        for (int k = tid >> 5; k < 512; k += 16)
            Rl[sgc * RSTR + k] = Rd[(size_t)k * G_ + gcol];
    }
    float bias4[4];
    #pragma unroll
    for (int g = 0; g < 4; ++g) bias4[g] = bd[g * 512 + u0 + fuu];

    float c_reg = 0.0f;
    const float4* Rl4  = reinterpret_cast<const float4*>(Rl);
    const float4* HA4  = reinterpret_cast<const float4*>(HA);
    const float4* Wel4 = reinterpret_cast<const float4*>(Wel);
    float4* HAw4 = reinterpret_cast<float4*>(HA);   // staging writes
    float4* P4s = reinterpret_cast<float4*>(Wel);   // scan reduce buffer (16 KB)
    float4* P4p = reinterpret_cast<float4*>(HA);    // precompute reduce buffer (64 KB)

    __syncthreads();

    const int nch = T_ / CH;
    for (int ch = 0; ch < nch; ++ch) {
        // ============ precompute xz = e@W for this chunk (k-split-8 GEMM) ============
        const int nat = CH >> 1;                     // A-tiles of 2t x 32b
        for (int at = 0; at < nat; ++at) {
            __syncthreads();                         // HA & Wel free
            for (int i = 0; i < 8; ++i) {
                int rr   = wv * 8 + i;
                int tloc = at * 2 + (rr >> 5);
                int bla  = rr & 31;
                int sg   = ch * CH + tloc;
                int tea  = dir ? (T_ - 1 - sg) : sg;
                int tok  = x[(b0base + bla) * T_ + tea];
                GLDS16(emb + (size_t)tok * E_ + lane * 4, HA + rr * ASTR);
            }
            float pacc[8][4];
            #pragma unroll
            for (int j = 0; j < 8; ++j)
                #pragma unroll
                for (int g = 0; g < 4; ++g) pacc[j][g] = 0.0f;

            for (int kh = 0; kh < 2; ++kh) {
                if (kh) __syncthreads();             // Wel half-0 reads done
                {
                    const int sgc  = tid & 31;
                    const int gcol = ((sgc >> 3) * 512) + u0 + (sgc & 7);
                    for (int kk = tid >> 5; kk < 128; kk += 16)
                        Wel[sgc * WESTR + kk] = Wd[(size_t)(kh * 128 + kk) * G_ + gcol];
                }
                __syncthreads();                     // A (vmcnt drained) + Wel ready
                #pragma unroll
                for (int k4 = 0; k4 < 4; ++k4) {
                    const int kw = wv * 4 + k4;
                    float4 w0 = Wel4[(0 * 8 + uu) * 33 + kw];
                    float4 w1 = Wel4[(1 * 8 + uu) * 33 + kw];
                    float4 w2 = Wel4[(2 * 8 + uu) * 33 + kw];
                    float4 w3 = Wel4[(3 * 8 + uu) * 33 + kw];
                    #pragma unroll
                    for (int j = 0; j < 8; ++j) {
                        float4 a = HA4[(blgrp + 8 * j) * 65 + kh * 32 + kw];
                        pacc[j][0] = fmaf(w0.x,a.x,pacc[j][0]); pacc[j][0] = fmaf(w0.y,a.y,pacc[j][0]);
                        pacc[j][0] = fmaf(w0.z,a.z,pacc[j][0]); pacc[j][0] = fmaf(w0.w,a.w,pacc[j][0]);
                        pacc[j][1] = fmaf(w1.x,a.x,pacc[j][1]); pacc[j][1] = fmaf(w1.y,a.y,pacc[j][1]);
                        pacc[j][1] = fmaf(w1.z,a.z,pacc[j][1]); pacc[j][1] = fmaf(w1.w,a.w,pacc[j][1]);
                        pacc[j][2] = fmaf(w2.x,a.x,pacc[j][2]); pacc[j][2] = fmaf(w2.y,a.y,pacc[j][2]);
                        pacc[j][2] = fmaf(w2.z,a.z,pacc[j][2]); pacc[j][2] = fmaf(w2.w,a.w,pacc[j][2]);
                        pacc[j][3] = fmaf(w3.x,a.x,pacc[j][3]); pacc[j][3] = fmaf(w3.y,a.y,pacc[j][3]);
                        pacc[j][3] = fmaf(w3.z,a.z,pacc[j][3]); pacc[j][3] = fmaf(w3.w,a.w,pacc[j][3]);
                    }
                }
            }
            __syncthreads();                         // A reads done -> HA reusable
            #pragma unroll
            for (int j = 0; j < 8; ++j)
                P4p[(wv * 64 + blgrp + 8 * j) * 8 + uu] =
                    float4{pacc[j][0], pacc[j][1], pacc[j][2], pacc[j][3]};
            __syncthreads();                         // partials ready
            {
                const int r   = tid >> 3;            // token row 0..63
                const int uq  = tid & 7;
                const int tl  = at * 2 + (r >> 5);
                const int bla = r & 31;
                float* dst = xz + ((size_t)blk * CH + tl) * 1024;
                float4 s = P4p[(0 * 64 + r) * 8 + uq];
                #pragma unroll
                for (int q = 1; q < 8; ++q) {
                    float4 p = P4p[(q * 64 + r) * 8 + uq];
                    s.x += p.x; s.y += p.y; s.z += p.z; s.w += p.w;
                }
                dst[(0 * 8 + uq) * 32 + bla] = s.x;
                dst[(1 * 8 + uq) * 32 + bla] = s.y;
                dst[(2 * 8 + uq) * 32 + bla] = s.z;
                dst[(3 * 8 + uq) * 32 + bla] = s.w;
            }
        }
        __syncthreads();

        // ============ scan CH steps ============
        for (int sc = 0; sc < CH; ++sc) {
            const int s   = ch * CH + sc;
            const int te  = dir ? (T_ - 1 - s) : s;
            const int cur = s & 1, nxt = cur ^ 1;

            // hoisted: barrier-independent loads (finalize threads only)
            int mtok = 0;
            float xzv[4] = {0.f, 0.f, 0.f, 0.f};
            if (tid < 256) {
                mtok = x[(b0base + blf) * T_ + te];
                const float* xzp = xz + ((size_t)blk * CH + sc) * 1024;
                #pragma unroll
                for (int g = 0; g < 4; ++g)
                    xzv[g] = xzp[(g * 8 + fuu) * 32 + blf] + bias4[g];
            }

            // wait: all 64 group members published h_s
            if (s > 0) {
                if (tid < 64) {
                    unsigned* slot = bar + (grp * 64 + tid) * 16;
                    while (__hip_atomic_load(slot, __ATOMIC_RELAXED,
                                             __HIP_MEMORY_SCOPE_AGENT) < (unsigned)s)
                        __builtin_amdgcn_s_sleep(1);
                }
                __syncthreads();
            }

            // stage h_s -> HA via agent-scope (L2-bypassing) loads + ds_write_b128
            {
                const char* hsrc = (const char*)(hbuf +
                    ((size_t)(cur * 2 + dir) * B_ + b0base) * U_);
                #pragma unroll
                for (int i = 0; i < 8; ++i) {
                    int off16 = (wv * 8 + i) * 64 + lane;    // float4 idx in 64KB
                    int row   = off16 >> 7;                  // 128 float4 per row
                    int col4  = off16 & 127;
                    const unsigned long long* p =
                        (const unsigned long long*)(hsrc + (size_t)off16 * 16);
                    unsigned long long a = __hip_atomic_load(p,     __ATOMIC_RELAXED,
                                                             __HIP_MEMORY_SCOPE_AGENT);
                    unsigned long long b = __hip_atomic_load(p + 1, __ATOMIC_RELAXED,
                                                             __HIP_MEMORY_SCOPE_AGENT);
                    float2 fa = __builtin_bit_cast(float2, a);
                    float2 fb = __builtin_bit_cast(float2, b);
                    HAw4[row * 129 + col4] = float4{fa.x, fa.y, fb.x, fb.y};
                }
            }
            __syncthreads();                         // h staged in LDS

            // partial z: this wave's 64-k slice, rows blgrp+8j, cols g*8+uu
            float pz[4][4];
            #pragma unroll
            for (int j = 0; j < 4; ++j)
                #pragma unroll
                for (int g = 0; g < 4; ++g) pz[j][g] = 0.0f;
            const int kbase = wv * 16;
            #pragma unroll 4
            for (int k4 = 0; k4 < 16; ++k4) {
                const int kk = kbase + k4;
                float4 h0 = HA4[(blgrp + 8 * 0) * 129 + kk];
                float4 h1 = HA4[(blgrp + 8 * 1) * 129 + kk];
                float4 h2 = HA4[(blgrp + 8 * 2) * 129 + kk];
                float4 h3 = HA4[(blgrp + 8 * 3) * 129 + kk];
                #pragma unroll
                for (int g = 0; g < 4; ++g) {
                    float4 w = Rl4[(g * 8 + uu) * 129 + kk];
                    pz[0][g] = fmaf(w.x,h0.x,pz[0][g]); pz[0][g] = fmaf(w.y,h0.y,pz[0][g]);
                    pz[0][g] = fmaf(w.z,h0.z,pz[0][g]); pz[0][g] = fmaf(w.w,h0.w,pz[0][g]);
                    pz[1][g] = fmaf(w.x,h1.x,pz[1][g]); pz[1][g] = fmaf(w.y,h1.y,pz[1][g]);
                    pz[1][g] = fmaf(w.z,h1.z,pz[1][g]); pz[1][g] = fmaf(w.w,h1.w,pz[1][g]);
                    pz[2][g] = fmaf(w.x,h2.x,pz[2][g]); pz[2][g] = fmaf(w.y,h2.y,pz[2][g]);
                    pz[2][g] = fmaf(w.z,h2.z,pz[2][g]); pz[2][g] = fmaf(w.w,h2.w,pz[2][g]);
                    pz[3][g] = fmaf(w.x,h3.x,pz[3][g]); pz[3][g] = fmaf(w.y,h3.y,pz[3][g]);
                    pz[3][g] = fmaf(w.z,h3.z,pz[3][g]); pz[3][g] = fmaf(w.w,h3.w,pz[3][g]);
                }
            }
            float h_old = (tid < 256) ? HA[blf * RSTR + u0 + fuu] : 0.0f;

            // two-phase k-reduce into 16KB P4s: waves 4-7 write, waves 0-3 RMW
            if (wv >= 4) {
                #pragma unroll
                for (int j = 0; j < 4; ++j)
                    P4s[((wv - 4) * 32 + blgrp + 8 * j) * 8 + uu] =
                        float4{pz[j][0], pz[j][1], pz[j][2], pz[j][3]};
            }
            __syncthreads();
            if (wv < 4) {
                #pragma unroll
                for (int j = 0; j < 4; ++j) {
                    const int idx = (wv * 32 + blgrp + 8 * j) * 8 + uu;
                    float4 t = P4s[idx];
                    t.x += pz[j][0]; t.y += pz[j][1];
                    t.z += pz[j][2]; t.w += pz[j][3];
                    P4s[idx] = t;
                }
            }
            __syncthreads();                         // partials ready

            float hsel = 0.0f;                       // kept live across the barrier
            if (tid < 256) {
                float4 z0 = P4s[(0 * 32 + blf) * 8 + fuu];
                float4 z1 = P4s[(1 * 32 + blf) * 8 + fuu];
                float4 z2 = P4s[(2 * 32 + blf) * 8 + fuu];
                float4 z3 = P4s[(3 * 32 + blf) * 8 + fuu];
                float fi = tanhf(z0.x + z1.x + z2.x + z3.x + xzv[0]);
                float ff = tanhf(z0.y + z1.y + z2.y + z3.y + xzv[1]);
                float fg = tanhf(z0.z + z1.z + z2.z + z3.z + xzv[2]);
                float fo = tanhf(z0.w + z1.w + z2.w + z3.w + xzv[3]);
                float cn = fmaf(ff, c_reg, fi * fg);
                float hn = fo * tanhf(cn);
                bool  m  = (mtok != 0);
                hsel  = m ? hn : h_old;
                c_reg = m ? cn : c_reg;

                // CRITICAL PATH: only the h store before the drain+publish
                const int b = b0base + blf;
                __hip_atomic_store(&hbuf[((size_t)(nxt * 2 + dir) * B_ + b) * U_ + u0 + fuu],
                                   hsel, __ATOMIC_RELAXED, __HIP_MEMORY_SCOPE_AGENT);
            }

            __syncthreads();       // vmcnt(0) drain: h write-through complete
            if (tid == 0)
                __hip_atomic_store(myslot, (unsigned)(s + 1), __ATOMIC_RELAXED,
                                   __HIP_MEMORY_SCOPE_AGENT);

            // OFF critical path: out stores drain at the NEXT step's barrier
            if (tid < 256) {
                const int b = b0base + blf;
                out[((size_t)b * T_ + te) * 1024 + dir * 512 + u0 + fuu] = hsel;
                if (dir == 1 && s == T_ - 1)
                    out[(size_t)B_ * T_ * 1024 + (size_t)b * U_ + u0 + fuu] = hsel;
            }
        }
    }
}

extern "C" void kernel_launch(void* const* d_in, const int* in_sizes, int n_in,
                              void* d_out, int out_size, void* d_ws, size_t ws_size,
                              hipStream_t stream) {
    const int*   x   = (const int*)d_in[0];
    const float* emb = (const float*)d_in[1];
    const float* Wf  = (const float*)d_in[2];
    const float* Rf  = (const float*)d_in[3];
    const float* bfp = (const float*)d_in[4];
    const float* Wb  = (const float*)d_in[5];
    const float* Rb  = (const float*)d_in[6];
    const float* bbp = (const float*)d_in[7];
    float* out  = (float*)d_out;
    float* hbuf = (float*)d_ws;                                   // 512 KB
    unsigned* bar = (unsigned*)((char*)d_ws + 512 * 1024);        // 16 KB
    float* xzbuf  = (float*)((char*)d_ws + (1 << 20));            // CH MB

    int CH = 32;
    while (CH > 2 && (size_t)(CH + 1) * (1 << 20) > ws_size) CH >>= 1;

    hipMemsetAsync(hbuf, 0, (size_t)2 * B_ * U_ * sizeof(float), stream);
    hipMemsetAsync(bar, 0, 4 * 64 * 16 * sizeof(unsigned), stream);

    void* args[] = {
        (void*)&x, (void*)&emb,
        (void*)&Wf, (void*)&Rf, (void*)&bfp,
        (void*)&Wb, (void*)&Rb, (void*)&bbp,
        (void*)&out, (void*)&hbuf, (void*)&bar, (void*)&xzbuf, (void*)&CH
    };
    hipLaunchCooperativeKernel((const void*)bilstm_kernel,
                               dim3(256), dim3(512), args, 0, stream);
}